// Round 2
// baseline (402.285 us; speedup 1.0000x reference)
//
#include <hip/hip_runtime.h>
#include <math.h>

#define BB   2
#define LL   1024
#define DD   1024
#define HH   16
#define HDIM 64
#define MM   (BB * LL)     // 2048
#define CHK  64            // chunk length
#define NCHK (LL / CHK)    // 16

// ---------------------------------------------------------------------------
// GEMM: C[M,N] = A[M,K] @ W[K,N], fp32, 64x64 tile, BK=16, 256 thr, 4x4 micro
// M, N, K all multiples of 64/64/16 (holds for all uses here).
// ---------------------------------------------------------------------------
__global__ __launch_bounds__(256) void gemm64(const float* __restrict__ A,
                                              const float* __restrict__ W,
                                              float* __restrict__ C,
                                              int N, int K) {
    __shared__ float As[16][64];
    __shared__ float Bs[16][64];
    const int tid = threadIdx.x;
    const int nb = N >> 6;
    const int bx = blockIdx.x % nb;
    const int by = blockIdx.x / nb;
    const int rowBase = by << 6, colBase = bx << 6;
    const int ty = tid >> 4, tx = tid & 15;
    const int arow = tid >> 2, ac = (tid & 3) << 2;   // A-stage: 64 rows x 4 f4
    const int brow = tid >> 4, bc = (tid & 15) << 2;  // B-stage: 16 rows x 16 f4
    float acc[4][4] = {};
    for (int k0 = 0; k0 < K; k0 += 16) {
        const float4 av = *(const float4*)&A[(size_t)(rowBase + arow) * K + k0 + ac];
        const float4 bv = *(const float4*)&W[(size_t)(k0 + brow) * N + colBase + bc];
        __syncthreads();
        As[ac + 0][arow] = av.x;
        As[ac + 1][arow] = av.y;
        As[ac + 2][arow] = av.z;
        As[ac + 3][arow] = av.w;
        *(float4*)&Bs[brow][bc] = bv;
        __syncthreads();
#pragma unroll
        for (int k = 0; k < 16; ++k) {
            float a[4], b[4];
#pragma unroll
            for (int i = 0; i < 4; ++i) a[i] = As[k][ty * 4 + i];
#pragma unroll
            for (int j = 0; j < 4; ++j) b[j] = Bs[k][tx * 4 + j];
#pragma unroll
            for (int i = 0; i < 4; ++i)
#pragma unroll
                for (int j = 0; j < 4; ++j)
                    acc[i][j] = fmaf(a[i], b[j], acc[i][j]);
        }
    }
#pragma unroll
    for (int i = 0; i < 4; ++i) {
        float4 o = make_float4(acc[i][0], acc[i][1], acc[i][2], acc[i][3]);
        *(float4*)&C[(size_t)(rowBase + ty * 4 + i) * N + colBase + tx * 4] = o;
    }
}

// ---------------------------------------------------------------------------
// beta[m,h] = sigmoid(x[m,:] @ Wb[:,h] + bb[h]);  m in [0,2048), h in [0,16)
// ---------------------------------------------------------------------------
__global__ void beta_kernel(const float* __restrict__ x,
                            const float* __restrict__ Wb,
                            const float* __restrict__ bb,
                            float* __restrict__ beta) {
    const int idx = blockIdx.x * 256 + threadIdx.x;   // 32768 total
    const int m = idx >> 4, h = idx & 15;
    float s = bb[h];
    const float* xr = x + (size_t)m * DD;
    for (int k = 0; k < DD; ++k) s = fmaf(xr[k], Wb[k * HH + h], s);
    beta[idx] = 1.0f / (1.0f + expf(-s));
}

// ---------------------------------------------------------------------------
// In-place L2 normalization of q and k per (b,l,h) over HD=64 contiguous
// elements. One wave (64 lanes) per row; 4 waves/block.
// rows: 0..M*H-1 -> q, M*H..2*M*H-1 -> k.  offset = r*64 + lane.
// Launch: 2*MM*HH rows total / 4 waves per block = 16384 blocks.
// ---------------------------------------------------------------------------
__global__ void l2norm_kernel(float* __restrict__ q, float* __restrict__ k) {
    const int wave = blockIdx.x * 4 + (threadIdx.x >> 6);
    const int lane = threadIdx.x & 63;
    float* base = (wave < MM * HH) ? q : k;
    const int r = (wave < MM * HH) ? wave : wave - MM * HH;
    const size_t off = (size_t)r * 64 + lane;
    const float v = base[off];
    float s = v * v;
#pragma unroll
    for (int o = 32; o > 0; o >>= 1) s += __shfl_xor(s, o, 64);
    base[off] = v / fmaxf(sqrtf(s), 1e-12f);
}

// ---------------------------------------------------------------------------
// Per-chunk KV sums: states[bh][c][d][e] = sum_{t in chunk} beta*k[t][d]*v[t][e]
// One block per (b,h,c). 64x64x(K=64) small GEMM in LDS.
// ---------------------------------------------------------------------------
__global__ __launch_bounds__(256) void chunkkv_kernel(const float* __restrict__ k,
                                                      const float* __restrict__ v,
                                                      const float* __restrict__ beta,
                                                      float* __restrict__ states) {
    const int c = blockIdx.x % NCHK;
    const int bh = blockIdx.x / NCHK;
    const int b = bh / HH, h = bh % HH;
    __shared__ float kb[64][65];
    __shared__ float vb[64][65];
    const int tid = threadIdx.x;
    for (int i = tid; i < 64 * 16; i += 256) {
        const int t = i >> 4, dg = (i & 15) << 2;
        const int m = b * LL + c * CHK + t;
        const float be = beta[m * HH + h];
        const float4 k4 = *(const float4*)&k[(size_t)m * DD + h * 64 + dg];
        const float4 v4 = *(const float4*)&v[(size_t)m * DD + h * 64 + dg];
        kb[t][dg + 0] = k4.x * be;
        kb[t][dg + 1] = k4.y * be;
        kb[t][dg + 2] = k4.z * be;
        kb[t][dg + 3] = k4.w * be;
        vb[t][dg + 0] = v4.x;
        vb[t][dg + 1] = v4.y;
        vb[t][dg + 2] = v4.z;
        vb[t][dg + 3] = v4.w;
    }
    __syncthreads();
    const int ty = tid >> 4, tx = tid & 15;
    float acc[4][4] = {};
    for (int t = 0; t < 64; ++t) {
        float a[4], bv[4];
#pragma unroll
        for (int i = 0; i < 4; ++i) a[i] = kb[t][ty * 4 + i];
#pragma unroll
        for (int j = 0; j < 4; ++j) bv[j] = vb[t][tx * 4 + j];
#pragma unroll
        for (int i = 0; i < 4; ++i)
#pragma unroll
            for (int j = 0; j < 4; ++j)
                acc[i][j] = fmaf(a[i], bv[j], acc[i][j]);
    }
    float* out = states + ((size_t)bh * NCHK + c) * 4096;
#pragma unroll
    for (int i = 0; i < 4; ++i) {
        float4 o = make_float4(acc[i][0], acc[i][1], acc[i][2], acc[i][3]);
        *(float4*)&out[(ty * 4 + i) * 64 + tx * 4] = o;
    }
}

// ---------------------------------------------------------------------------
// Exclusive prefix over chunks, in place. One block per (b,h).
// ---------------------------------------------------------------------------
__global__ void prefix_kernel(float* __restrict__ states) {
    float* base = states + (size_t)blockIdx.x * NCHK * 4096;
    const int tid = threadIdx.x;
    for (int j = 0; j < 16; ++j) {
        const int p = tid + j * 256;
        float run = 0.0f;
        for (int c = 0; c < NCHK; ++c) {
            const float val = base[c * 4096 + p];
            base[c * 4096 + p] = run;
            run += val;
        }
    }
}

// ---------------------------------------------------------------------------
// Per-chunk output: y[t][e] = q[t]·state + sum_{s<=t} (q_t·k_s) * beta_s * v_s[e]
// One block per (b,h,c). S is written back into kb's LDS space.
// ---------------------------------------------------------------------------
__global__ __launch_bounds__(256) void attn_kernel(const float* __restrict__ q,
                                                   const float* __restrict__ k,
                                                   const float* __restrict__ v,
                                                   const float* __restrict__ beta,
                                                   const float* __restrict__ states,
                                                   float* __restrict__ y) {
    const int c = blockIdx.x % NCHK;
    const int bh = blockIdx.x / NCHK;
    const int b = bh / HH, h = bh % HH;
    __shared__ float qb[64][65];
    __shared__ float kb[64][65];   // becomes S after the score phase
    __shared__ float vb[64][65];   // beta-weighted v
    __shared__ float st[64][65];
    const int tid = threadIdx.x;
    const float* stg = states + ((size_t)bh * NCHK + c) * 4096;
    for (int i = tid; i < 64 * 16; i += 256) {
        const int t = i >> 4, dg = (i & 15) << 2;
        const int m = b * LL + c * CHK + t;
        const size_t go = (size_t)m * DD + h * 64 + dg;
        const float be = beta[m * HH + h];
        const float4 q4 = *(const float4*)&q[go];
        const float4 k4 = *(const float4*)&k[go];
        const float4 v4 = *(const float4*)&v[go];
        const float4 s4 = *(const float4*)&stg[t * 64 + dg];
        qb[t][dg + 0] = q4.x; qb[t][dg + 1] = q4.y; qb[t][dg + 2] = q4.z; qb[t][dg + 3] = q4.w;
        kb[t][dg + 0] = k4.x; kb[t][dg + 1] = k4.y; kb[t][dg + 2] = k4.z; kb[t][dg + 3] = k4.w;
        vb[t][dg + 0] = v4.x * be; vb[t][dg + 1] = v4.y * be; vb[t][dg + 2] = v4.z * be; vb[t][dg + 3] = v4.w * be;
        st[t][dg + 0] = s4.x; st[t][dg + 1] = s4.y; st[t][dg + 2] = s4.z; st[t][dg + 3] = s4.w;
    }
    __syncthreads();
    const int ty = tid >> 4, tx = tid & 15;
    // S[t][s] = q_t · k_s  for tile t=ty*4.., s=tx*4..
    float acc[4][4] = {};
    for (int d = 0; d < 64; ++d) {
        float a[4], bv[4];
#pragma unroll
        for (int i = 0; i < 4; ++i) a[i] = qb[ty * 4 + i][d];
#pragma unroll
        for (int j = 0; j < 4; ++j) bv[j] = kb[tx * 4 + j][d];
#pragma unroll
        for (int i = 0; i < 4; ++i)
#pragma unroll
            for (int j = 0; j < 4; ++j)
                acc[i][j] = fmaf(a[i], bv[j], acc[i][j]);
    }
    __syncthreads();   // all reads of kb done
#pragma unroll
    for (int i = 0; i < 4; ++i)
#pragma unroll
        for (int j = 0; j < 4; ++j) {
            const int t = ty * 4 + i, s = tx * 4 + j;
            kb[t][s] = (s <= t) ? acc[i][j] : 0.0f;   // causal mask
        }
    __syncthreads();
    // O = S @ vb + qb @ st
    float o[4][4] = {};
    for (int s = 0; s < 64; ++s) {
        float a[4], bv[4];
#pragma unroll
        for (int i = 0; i < 4; ++i) a[i] = kb[ty * 4 + i][s];
#pragma unroll
        for (int j = 0; j < 4; ++j) bv[j] = vb[s][tx * 4 + j];
#pragma unroll
        for (int i = 0; i < 4; ++i)
#pragma unroll
            for (int j = 0; j < 4; ++j)
                o[i][j] = fmaf(a[i], bv[j], o[i][j]);
    }
    for (int d = 0; d < 64; ++d) {
        float a[4], bv[4];
#pragma unroll
        for (int i = 0; i < 4; ++i) a[i] = qb[ty * 4 + i][d];
#pragma unroll
        for (int j = 0; j < 4; ++j) bv[j] = st[d][tx * 4 + j];
#pragma unroll
        for (int i = 0; i < 4; ++i)
#pragma unroll
            for (int j = 0; j < 4; ++j)
                o[i][j] = fmaf(a[i], bv[j], o[i][j]);
    }
#pragma unroll
    for (int i = 0; i < 4; ++i) {
        const int m = b * LL + c * CHK + ty * 4 + i;
        float4 ov = make_float4(o[i][0], o[i][1], o[i][2], o[i][3]);
        *(float4*)&y[(size_t)m * DD + h * 64 + tx * 4] = ov;
    }
}

// ---------------------------------------------------------------------------
extern "C" void kernel_launch(void* const* d_in, const int* in_sizes, int n_in,
                              void* d_out, int out_size, void* d_ws, size_t ws_size,
                              hipStream_t stream) {
    (void)in_sizes; (void)n_in; (void)out_size; (void)ws_size;
    const float* x  = (const float*)d_in[0];
    const float* Wq = (const float*)d_in[1];
    const float* Wk = (const float*)d_in[2];
    const float* Wv = (const float*)d_in[3];
    const float* Wo = (const float*)d_in[4];
    const float* Wb = (const float*)d_in[5];
    const float* bb = (const float*)d_in[6];
    float* out = (float*)d_out;

    float* ws = (float*)d_ws;
    float* q      = ws;                          // 2048*1024
    float* kk     = q + (size_t)MM * DD;         // 2048*1024
    float* vv     = kk + (size_t)MM * DD;        // 2048*1024
    float* beta   = vv + (size_t)MM * DD;        // 2048*16
    float* states = beta + (size_t)MM * HH;      // 32*16*4096 = 2048*1024
    float* y      = states + (size_t)BB * HH * NCHK * 4096;  // 2048*1024

    const int gemm_blocks = (MM / 64) * (DD / 64);   // 512

    gemm64<<<gemm_blocks, 256, 0, stream>>>(x, Wq, q, DD, DD);
    gemm64<<<gemm_blocks, 256, 0, stream>>>(x, Wk, kk, DD, DD);
    gemm64<<<gemm_blocks, 256, 0, stream>>>(x, Wv, vv, DD, DD);
    beta_kernel<<<(MM * HH) / 256, 256, 0, stream>>>(x, Wb, bb, beta);
    l2norm_kernel<<<(2 * MM * HH) / 4, 256, 0, stream>>>(q, kk);   // 16384 blocks
    chunkkv_kernel<<<BB * HH * NCHK, 256, 0, stream>>>(kk, vv, beta, states);
    prefix_kernel<<<BB * HH, 256, 0, stream>>>(states);
    attn_kernel<<<BB * HH * NCHK, 256, 0, stream>>>(q, kk, vv, beta, states, y);
    gemm64<<<gemm_blocks, 256, 0, stream>>>(y, Wo, out, DD, DD);
}

// Round 3
// 187.773 us; speedup vs baseline: 2.1424x; 2.1424x over previous
//
#include <hip/hip_runtime.h>
#include <math.h>

#define BB   2
#define LL   1024
#define DD   1024
#define HH   16
#define HDIM 64
#define MM   (BB * LL)     // 2048
#define CHK  64            // chunk length
#define NCHK (LL / CHK)    // 16

typedef short bf16x8 __attribute__((ext_vector_type(8)));
typedef float f32x4  __attribute__((ext_vector_type(4)));
typedef const __attribute__((address_space(1))) unsigned int* gas_ptr;
typedef __attribute__((address_space(3))) unsigned int* las_ptr;

__device__ __forceinline__ void gload16(const void* g, void* l) {
    // async global->LDS, 16B per lane; LDS dest must be wave-uniform base + lane*16
    __builtin_amdgcn_global_load_lds((gas_ptr)(unsigned long long)g,
                                     (las_ptr)(unsigned long long)l, 16, 0, 0);
}

__device__ __forceinline__ unsigned short f2bf(float f) {
    unsigned int u = __float_as_uint(f);
    u += 0x7fffu + ((u >> 16) & 1u);      // RNE
    return (unsigned short)(u >> 16);
}
__device__ __forceinline__ float bfhi(unsigned int u) { return __uint_as_float(u & 0xffff0000u); }
__device__ __forceinline__ float bflo(unsigned int u) { return __uint_as_float(u << 16); }

// ---------------------------------------------------------------------------
// prep: cast x (fp32->bf16) and transpose Wb (1024x16 -> 16x1024 fp32)
// ---------------------------------------------------------------------------
__global__ void prep_kernel(const float* __restrict__ x, unsigned short* __restrict__ xb,
                            const float* __restrict__ Wb, float* __restrict__ Wbt) {
    const int bid = blockIdx.x;
    if (bid < 2048) {
        const int idx = bid * 256 + threadIdx.x;     // 524288 float4s
        const float4 v = ((const float4*)x)[idx];
        ushort4 o;
        o.x = f2bf(v.x); o.y = f2bf(v.y); o.z = f2bf(v.z); o.w = f2bf(v.w);
        ((ushort4*)xb)[idx] = o;
    } else {
        const int t = (bid - 2048) * 256 + threadIdx.x;   // 16384 = 16*1024
        const int h = t >> 10, k = t & 1023;
        Wbt[t] = Wb[k * HH + h];
    }
}

// ---------------------------------------------------------------------------
// transpose+cast the 4 square weights: W[k][n] fp32 -> Wt[n][k] bf16
// grid: 4 * 1024 blocks (32x32 tiles), 256 threads
// ---------------------------------------------------------------------------
__global__ void transpose_cast(const float* __restrict__ W0, const float* __restrict__ W1,
                               const float* __restrict__ W2, const float* __restrict__ W3,
                               unsigned short* __restrict__ T0, unsigned short* __restrict__ T1,
                               unsigned short* __restrict__ T2, unsigned short* __restrict__ T3) {
    __shared__ float tile[32][33];
    const int which = blockIdx.x >> 10;
    const int b = blockIdx.x & 1023;
    const int bk = b >> 5, bn = b & 31;
    const float* W = which == 0 ? W0 : which == 1 ? W1 : which == 2 ? W2 : W3;
    unsigned short* T = which == 0 ? T0 : which == 1 ? T1 : which == 2 ? T2 : T3;
    const int tx = threadIdx.x & 31, ty = threadIdx.x >> 5;   // ty: 0..7
#pragma unroll
    for (int i = 0; i < 4; ++i)
        tile[ty + i * 8][tx] = W[(size_t)(bk * 32 + ty + i * 8) * DD + bn * 32 + tx];
    __syncthreads();
#pragma unroll
    for (int i = 0; i < 4; ++i)
        T[(size_t)(bn * 32 + ty + i * 8) * DD + bk * 32 + tx] = f2bf(tile[tx][ty + i * 8]);
}

// ---------------------------------------------------------------------------
// bf16 MFMA GEMM K-loop (m97 structure): 128x128 tile, BK=32, 256 thr, 4 waves.
// A: [M][K] bf16 row-major; Bt: [N][K] bf16 row-major. acc in fp32.
// ---------------------------------------------------------------------------
__device__ __forceinline__ void gemm_kloop(const unsigned short* A, const unsigned short* Bt,
                                           unsigned short* As, unsigned short* Bs,
                                           int rowBase, int colBase, int K,
                                           f32x4 acc[4][4]) {
    const int tid = threadIdx.x;
    const int c0 = tid, c1 = tid + 256;
    const int ar0 = c0 >> 2, ak0 = (c0 & 3) << 3;
    const int ar1 = c1 >> 2, ak1 = (c1 & 3) << 3;
    const unsigned short* Ag0 = A + (size_t)(rowBase + ar0) * K + ak0;
    const unsigned short* Ag1 = A + (size_t)(rowBase + ar1) * K + ak1;
    const unsigned short* Bg0 = Bt + (size_t)(colBase + ar0) * K + ak0;
    const unsigned short* Bg1 = Bt + (size_t)(colBase + ar1) * K + ak1;
    unsigned short* Al0 = As + c0 * 8; unsigned short* Al1 = As + c1 * 8;
    unsigned short* Bl0 = Bs + c0 * 8; unsigned short* Bl1 = Bs + c1 * 8;
    const int lane = tid & 63, wv = tid >> 6;
    const int qr = wv >> 1, qc = wv & 1;
    const int fr = lane & 15;
    const int koff = (lane >> 4) << 3;    // 0,8,16,24
    int aoff[4], boff[4];
#pragma unroll
    for (int mi = 0; mi < 4; ++mi) aoff[mi] = (qr * 64 + mi * 16 + fr) * 32 + koff;
#pragma unroll
    for (int nj = 0; nj < 4; ++nj) boff[nj] = (qc * 64 + nj * 16 + fr) * 32 + koff;

    for (int k0 = 0; k0 < K; k0 += 32) {
        __syncthreads();                      // prev-iter LDS reads done
        gload16(Ag0, Al0); gload16(Ag1, Al1);
        gload16(Bg0, Bl0); gload16(Bg1, Bl1);
        Ag0 += 32; Ag1 += 32; Bg0 += 32; Bg1 += 32;
        __syncthreads();                      // loads landed
        bf16x8 av[4], bv[4];
#pragma unroll
        for (int mi = 0; mi < 4; ++mi) av[mi] = *(const bf16x8*)(As + aoff[mi]);
#pragma unroll
        for (int nj = 0; nj < 4; ++nj) bv[nj] = *(const bf16x8*)(Bs + boff[nj]);
#pragma unroll
        for (int mi = 0; mi < 4; ++mi)
#pragma unroll
            for (int nj = 0; nj < 4; ++nj)
                acc[mi][nj] = __builtin_amdgcn_mfma_f32_16x16x32_bf16(av[mi], bv[nj], acc[mi][nj], 0, 0, 0);
    }
}

// ---------------------------------------------------------------------------
// Fused q/k/v projection GEMM with per-head L2-norm epilogue for q,k.
// grid = 16 (M-tiles) * 24 (3 mats * 8 N-tiles). Output bf16.
// ---------------------------------------------------------------------------
__global__ __launch_bounds__(256) void gemm_qkv(const unsigned short* __restrict__ xb,
                                                const unsigned short* __restrict__ Wqt,
                                                const unsigned short* __restrict__ Wkt,
                                                const unsigned short* __restrict__ Wvt,
                                                unsigned short* __restrict__ qb,
                                                unsigned short* __restrict__ kb,
                                                unsigned short* __restrict__ vb) {
    __shared__ unsigned short As[128 * 32];
    __shared__ unsigned short Bs[128 * 32];
    const int by = blockIdx.x / 24, bxx = blockIdx.x % 24;
    const int mat = bxx >> 3, tn = bxx & 7;
    const unsigned short* Bt = mat == 0 ? Wqt : (mat == 1 ? Wkt : Wvt);
    unsigned short* Cout = mat == 0 ? qb : (mat == 1 ? kb : vb);
    f32x4 acc[4][4];
#pragma unroll
    for (int mi = 0; mi < 4; ++mi)
#pragma unroll
        for (int nj = 0; nj < 4; ++nj) acc[mi][nj] = (f32x4){0.f, 0.f, 0.f, 0.f};
    gemm_kloop(xb, Bt, As, Bs, by * 128, tn * 128, DD, acc);

    const int lane = threadIdx.x & 63, wv = threadIdx.x >> 6;
    const int qr = wv >> 1, qc = wv & 1;
    if (mat < 2) {
        // Each wave's 64 cols == one full head; rows are (quad*4+i). L2-normalize.
#pragma unroll
        for (int mi = 0; mi < 4; ++mi)
#pragma unroll
            for (int i = 0; i < 4; ++i) {
                float s = 0.f;
#pragma unroll
                for (int nj = 0; nj < 4; ++nj) { float t = acc[mi][nj][i]; s += t * t; }
                s += __shfl_xor(s, 1, 64);
                s += __shfl_xor(s, 2, 64);
                s += __shfl_xor(s, 4, 64);
                s += __shfl_xor(s, 8, 64);
                const float inv = 1.0f / fmaxf(sqrtf(s), 1e-12f);
#pragma unroll
                for (int nj = 0; nj < 4; ++nj) acc[mi][nj][i] *= inv;
            }
    }
#pragma unroll
    for (int mi = 0; mi < 4; ++mi)
#pragma unroll
        for (int i = 0; i < 4; ++i) {
            const int row = by * 128 + qr * 64 + mi * 16 + (lane >> 4) * 4 + i;
#pragma unroll
            for (int nj = 0; nj < 4; ++nj) {
                const int col = tn * 128 + qc * 64 + nj * 16 + (lane & 15);
                Cout[(size_t)row * DD + col] = f2bf(acc[mi][nj][i]);
            }
        }
}

// ---------------------------------------------------------------------------
// Output GEMM: out = y(bf16) @ Wo -> fp32. grid = 16*8 = 128.
// ---------------------------------------------------------------------------
__global__ __launch_bounds__(256) void gemm_out(const unsigned short* __restrict__ yb,
                                                const unsigned short* __restrict__ Wot,
                                                float* __restrict__ out) {
    __shared__ unsigned short As[128 * 32];
    __shared__ unsigned short Bs[128 * 32];
    const int by = blockIdx.x >> 3, tn = blockIdx.x & 7;
    f32x4 acc[4][4];
#pragma unroll
    for (int mi = 0; mi < 4; ++mi)
#pragma unroll
        for (int nj = 0; nj < 4; ++nj) acc[mi][nj] = (f32x4){0.f, 0.f, 0.f, 0.f};
    gemm_kloop(yb, Wot, As, Bs, by * 128, tn * 128, DD, acc);
    const int lane = threadIdx.x & 63, wv = threadIdx.x >> 6;
    const int qr = wv >> 1, qc = wv & 1;
#pragma unroll
    for (int mi = 0; mi < 4; ++mi)
#pragma unroll
        for (int i = 0; i < 4; ++i) {
            const int row = by * 128 + qr * 64 + mi * 16 + (lane >> 4) * 4 + i;
#pragma unroll
            for (int nj = 0; nj < 4; ++nj) {
                const int col = tn * 128 + qc * 64 + nj * 16 + (lane & 15);
                out[(size_t)row * DD + col] = acc[mi][nj][i];
            }
        }
}

// ---------------------------------------------------------------------------
// beta[m,h] = sigmoid(x[m,:] @ Wbt[h,:] + bb[h]); one wave per row m.
// ---------------------------------------------------------------------------
__global__ void beta_kernel(const float* __restrict__ x, const float* __restrict__ Wbt,
                            const float* __restrict__ bias, float* __restrict__ beta) {
    const int m = blockIdx.x * 4 + (threadIdx.x >> 6);
    const int lane = threadIdx.x & 63;
    const float4* xr = (const float4*)(x + (size_t)m * DD);
    float4 xv[4];
#pragma unroll
    for (int i = 0; i < 4; ++i) xv[i] = xr[lane * 4 + i];
    float res = 0.f;
#pragma unroll
    for (int h = 0; h < HH; ++h) {
        const float4* wr = (const float4*)(Wbt + (size_t)h * DD);
        float s = 0.f;
#pragma unroll
        for (int i = 0; i < 4; ++i) {
            const float4 w = wr[lane * 4 + i];
            s += xv[i].x * w.x + xv[i].y * w.y + xv[i].z * w.z + xv[i].w * w.w;
        }
        s += __shfl_xor(s, 1, 64);  s += __shfl_xor(s, 2, 64);
        s += __shfl_xor(s, 4, 64);  s += __shfl_xor(s, 8, 64);
        s += __shfl_xor(s, 16, 64); s += __shfl_xor(s, 32, 64);
        if (lane == h) res = s;
    }
    if (lane < HH) beta[m * HH + lane] = 1.0f / (1.0f + expf(-(res + bias[lane])));
}

// ---------------------------------------------------------------------------
// Per-chunk KV sums: states[bh][c][d][e] = sum_t beta*k[t][d]*v[t][e]  (bf16 in)
// ---------------------------------------------------------------------------
__global__ __launch_bounds__(256) void chunkkv_kernel(const unsigned short* __restrict__ k,
                                                      const unsigned short* __restrict__ v,
                                                      const float* __restrict__ beta,
                                                      float* __restrict__ states) {
    const int c = blockIdx.x % NCHK;
    const int bh = blockIdx.x / NCHK;
    const int b = bh / HH, h = bh % HH;
    __shared__ float kb[64][65];
    __shared__ float vb[64][65];
    const int tid = threadIdx.x;
    for (int i = tid; i < 512; i += 256) {
        const int t = i >> 3, dg = (i & 7) << 3;
        const int m = b * LL + c * CHK + t;
        const float be = beta[m * HH + h];
        const size_t go = (size_t)m * DD + h * 64 + dg;
        const uint4 ku = *(const uint4*)&k[go];
        const uint4 vu = *(const uint4*)&v[go];
        kb[t][dg + 0] = bflo(ku.x) * be; kb[t][dg + 1] = bfhi(ku.x) * be;
        kb[t][dg + 2] = bflo(ku.y) * be; kb[t][dg + 3] = bfhi(ku.y) * be;
        kb[t][dg + 4] = bflo(ku.z) * be; kb[t][dg + 5] = bfhi(ku.z) * be;
        kb[t][dg + 6] = bflo(ku.w) * be; kb[t][dg + 7] = bfhi(ku.w) * be;
        vb[t][dg + 0] = bflo(vu.x); vb[t][dg + 1] = bfhi(vu.x);
        vb[t][dg + 2] = bflo(vu.y); vb[t][dg + 3] = bfhi(vu.y);
        vb[t][dg + 4] = bflo(vu.z); vb[t][dg + 5] = bfhi(vu.z);
        vb[t][dg + 6] = bflo(vu.w); vb[t][dg + 7] = bfhi(vu.w);
    }
    __syncthreads();
    const int ty = tid >> 4, tx = tid & 15;
    float acc[4][4] = {};
    for (int t = 0; t < 64; ++t) {
        float a[4], bv[4];
#pragma unroll
        for (int i = 0; i < 4; ++i) a[i] = kb[t][ty * 4 + i];
#pragma unroll
        for (int j = 0; j < 4; ++j) bv[j] = vb[t][tx * 4 + j];
#pragma unroll
        for (int i = 0; i < 4; ++i)
#pragma unroll
            for (int j = 0; j < 4; ++j)
                acc[i][j] = fmaf(a[i], bv[j], acc[i][j]);
    }
    float* out = states + ((size_t)bh * NCHK + c) * 4096;
#pragma unroll
    for (int i = 0; i < 4; ++i) {
        float4 o = make_float4(acc[i][0], acc[i][1], acc[i][2], acc[i][3]);
        *(float4*)&out[(ty * 4 + i) * 64 + tx * 4] = o;
    }
}

// ---------------------------------------------------------------------------
// Exclusive prefix over chunks, in place. One block per (b,h).
// ---------------------------------------------------------------------------
__global__ void prefix_kernel(float* __restrict__ states) {
    float* base = states + (size_t)blockIdx.x * NCHK * 4096;
    const int tid = threadIdx.x;
    for (int j = 0; j < 16; ++j) {
        const int p = tid + j * 256;
        float run = 0.0f;
        for (int c = 0; c < NCHK; ++c) {
            const float val = base[c * 4096 + p];
            base[c * 4096 + p] = run;
            run += val;
        }
    }
}

// ---------------------------------------------------------------------------
// Per-chunk output (bf16 q/k/v in, bf16 y out):
// y[t][e] = q[t]·state + sum_{s<=t} (q_t·k_s) * beta_s * v_s[e]
// ---------------------------------------------------------------------------
__global__ __launch_bounds__(256) void attn_kernel(const unsigned short* __restrict__ q,
                                                   const unsigned short* __restrict__ k,
                                                   const unsigned short* __restrict__ v,
                                                   const float* __restrict__ beta,
                                                   const float* __restrict__ states,
                                                   unsigned short* __restrict__ y) {
    const int c = blockIdx.x % NCHK;
    const int bh = blockIdx.x / NCHK;
    const int b = bh / HH, h = bh % HH;
    __shared__ float qb[64][65];
    __shared__ float kb[64][65];   // becomes S after the score phase
    __shared__ float vb[64][65];   // beta-weighted v
    __shared__ float st[64][65];
    const int tid = threadIdx.x;
    const float* stg = states + ((size_t)bh * NCHK + c) * 4096;
    for (int i = tid; i < 512; i += 256) {
        const int t = i >> 3, dg = (i & 7) << 3;
        const int m = b * LL + c * CHK + t;
        const float be = beta[m * HH + h];
        const size_t go = (size_t)m * DD + h * 64 + dg;
        const uint4 qu = *(const uint4*)&q[go];
        const uint4 ku = *(const uint4*)&k[go];
        const uint4 vu = *(const uint4*)&v[go];
        qb[t][dg + 0] = bflo(qu.x); qb[t][dg + 1] = bfhi(qu.x);
        qb[t][dg + 2] = bflo(qu.y); qb[t][dg + 3] = bfhi(qu.y);
        qb[t][dg + 4] = bflo(qu.z); qb[t][dg + 5] = bfhi(qu.z);
        qb[t][dg + 6] = bflo(qu.w); qb[t][dg + 7] = bfhi(qu.w);
        kb[t][dg + 0] = bflo(ku.x); kb[t][dg + 1] = bfhi(ku.x);
        kb[t][dg + 2] = bflo(ku.y); kb[t][dg + 3] = bfhi(ku.y);
        kb[t][dg + 4] = bflo(ku.z); kb[t][dg + 5] = bfhi(ku.z);
        kb[t][dg + 6] = bflo(ku.w); kb[t][dg + 7] = bfhi(ku.w);
        vb[t][dg + 0] = bflo(vu.x) * be; vb[t][dg + 1] = bfhi(vu.x) * be;
        vb[t][dg + 2] = bflo(vu.y) * be; vb[t][dg + 3] = bfhi(vu.y) * be;
        vb[t][dg + 4] = bflo(vu.z) * be; vb[t][dg + 5] = bfhi(vu.z) * be;
        vb[t][dg + 6] = bflo(vu.w) * be; vb[t][dg + 7] = bfhi(vu.w) * be;
    }
    for (int i = tid; i < 1024; i += 256) {
        const int t = i >> 4, dg = (i & 15) << 2;
        const float4 s4 = *(const float4*)&stg[t * 64 + dg];
        st[t][dg + 0] = s4.x; st[t][dg + 1] = s4.y; st[t][dg + 2] = s4.z; st[t][dg + 3] = s4.w;
    }
    __syncthreads();
    const int ty = tid >> 4, tx = tid & 15;
    float acc[4][4] = {};
    for (int d = 0; d < 64; ++d) {
        float a[4], bv[4];
#pragma unroll
        for (int i = 0; i < 4; ++i) a[i] = qb[ty * 4 + i][d];
#pragma unroll
        for (int j = 0; j < 4; ++j) bv[j] = kb[tx * 4 + j][d];
#pragma unroll
        for (int i = 0; i < 4; ++i)
#pragma unroll
            for (int j = 0; j < 4; ++j)
                acc[i][j] = fmaf(a[i], bv[j], acc[i][j]);
    }
    __syncthreads();
#pragma unroll
    for (int i = 0; i < 4; ++i)
#pragma unroll
        for (int j = 0; j < 4; ++j) {
            const int t = ty * 4 + i, s = tx * 4 + j;
            kb[t][s] = (s <= t) ? acc[i][j] : 0.0f;
        }
    __syncthreads();
    float o[4][4] = {};
    for (int s = 0; s < 64; ++s) {
        float a[4], bv[4];
#pragma unroll
        for (int i = 0; i < 4; ++i) a[i] = kb[ty * 4 + i][s];
#pragma unroll
        for (int j = 0; j < 4; ++j) bv[j] = vb[s][tx * 4 + j];
#pragma unroll
        for (int i = 0; i < 4; ++i)
#pragma unroll
            for (int j = 0; j < 4; ++j)
                o[i][j] = fmaf(a[i], bv[j], o[i][j]);
    }
    for (int d = 0; d < 64; ++d) {
        float a[4], bv[4];
#pragma unroll
        for (int i = 0; i < 4; ++i) a[i] = qb[ty * 4 + i][d];
#pragma unroll
        for (int j = 0; j < 4; ++j) bv[j] = st[d][tx * 4 + j];
#pragma unroll
        for (int i = 0; i < 4; ++i)
#pragma unroll
            for (int j = 0; j < 4; ++j)
                o[i][j] = fmaf(a[i], bv[j], o[i][j]);
    }
#pragma unroll
    for (int i = 0; i < 4; ++i) {
        const int m = b * LL + c * CHK + ty * 4 + i;
        ushort4 ov;
        ov.x = f2bf(o[i][0]); ov.y = f2bf(o[i][1]); ov.z = f2bf(o[i][2]); ov.w = f2bf(o[i][3]);
        *(ushort4*)&y[(size_t)m * DD + h * 64 + tx * 4] = ov;
    }
}

// ---------------------------------------------------------------------------
extern "C" void kernel_launch(void* const* d_in, const int* in_sizes, int n_in,
                              void* d_out, int out_size, void* d_ws, size_t ws_size,
                              hipStream_t stream) {
    (void)in_sizes; (void)n_in; (void)out_size; (void)ws_size;
    const float* x  = (const float*)d_in[0];
    const float* Wq = (const float*)d_in[1];
    const float* Wk = (const float*)d_in[2];
    const float* Wv = (const float*)d_in[3];
    const float* Wo = (const float*)d_in[4];
    const float* Wb = (const float*)d_in[5];
    const float* bbp = (const float*)d_in[6];
    float* out = (float*)d_out;

    char* ws = (char*)d_ws;
    unsigned short* xb  = (unsigned short*)ws;                      ws += (size_t)MM * DD * 2;   // 4MB
    unsigned short* Wqt = (unsigned short*)ws;                      ws += (size_t)DD * DD * 2;   // 2MB
    unsigned short* Wkt = (unsigned short*)ws;                      ws += (size_t)DD * DD * 2;
    unsigned short* Wvt = (unsigned short*)ws;                      ws += (size_t)DD * DD * 2;
    unsigned short* Wot = (unsigned short*)ws;                      ws += (size_t)DD * DD * 2;
    float*          Wbt = (float*)ws;                               ws += (size_t)HH * DD * 4;   // 64KB
    unsigned short* qb  = (unsigned short*)ws;                      ws += (size_t)MM * DD * 2;   // 4MB
    unsigned short* kb  = (unsigned short*)ws;                      ws += (size_t)MM * DD * 2;
    unsigned short* vb  = (unsigned short*)ws;                      ws += (size_t)MM * DD * 2;
    unsigned short* yb  = (unsigned short*)ws;                      ws += (size_t)MM * DD * 2;
    float*          beta   = (float*)ws;                            ws += (size_t)MM * HH * 4;   // 128KB
    float*          states = (float*)ws;                            ws += (size_t)BB * HH * NCHK * 4096 * 4; // 8MB

    prep_kernel<<<2112, 256, 0, stream>>>(x, xb, Wb, Wbt);
    transpose_cast<<<4096, 256, 0, stream>>>(Wq, Wk, Wv, Wo, Wqt, Wkt, Wvt, Wot);
    gemm_qkv<<<16 * 24, 256, 0, stream>>>(xb, Wqt, Wkt, Wvt, qb, kb, vb);
    beta_kernel<<<MM / 4, 256, 0, stream>>>(x, Wbt, bbp, beta);
    chunkkv_kernel<<<BB * HH * NCHK, 256, 0, stream>>>(kb, vb, beta, states);
    prefix_kernel<<<BB * HH, 256, 0, stream>>>(states);
    attn_kernel<<<BB * HH * NCHK, 256, 0, stream>>>(qb, kb, vb, beta, states, yb);
    gemm_out<<<16 * 8, 256, 0, stream>>>(yb, Wot, out);
}

// Round 4
// 155.296 us; speedup vs baseline: 2.5904x; 1.2091x over previous
//
#include <hip/hip_runtime.h>
#include <math.h>

#define BB   2
#define LL   1024
#define DD   1024
#define HH   16
#define HDIM 64
#define MM   (BB * LL)     // 2048
#define CHK  64            // chunk length
#define NCHK (LL / CHK)    // 16

typedef short bf16x8 __attribute__((ext_vector_type(8)));
typedef float f32x4  __attribute__((ext_vector_type(4)));
typedef const __attribute__((address_space(1))) unsigned int* gas_ptr;
typedef __attribute__((address_space(3))) unsigned int* las_ptr;

__device__ __forceinline__ void gload16(const void* g, void* l) {
    __builtin_amdgcn_global_load_lds((gas_ptr)(unsigned long long)g,
                                     (las_ptr)(unsigned long long)l, 16, 0, 0);
}

__device__ __forceinline__ unsigned short f2bf(float f) {
    unsigned int u = __float_as_uint(f);
    u += 0x7fffu + ((u >> 16) & 1u);      // RNE
    return (unsigned short)(u >> 16);
}
__device__ __forceinline__ float bfhi(unsigned int u) { return __uint_as_float(u & 0xffff0000u); }
__device__ __forceinline__ float bflo(unsigned int u) { return __uint_as_float(u << 16); }

// 8 bf16 from a [64][70]-strided LDS tile at [row][tc..tc+7]; 4-aligned only -> 4x b32
__device__ __forceinline__ bf16x8 frag70(const unsigned short* a, int row, int tc) {
    const unsigned int* p = (const unsigned int*)(a + row * 70 + tc);
    union { unsigned int u[4]; bf16x8 v; } r;
    r.u[0] = p[0]; r.u[1] = p[1]; r.u[2] = p[2]; r.u[3] = p[3];
    return r.v;
}

// ---------------------------------------------------------------------------
// prep: cast x (fp32->bf16) and transpose Wb (1024x16 -> 16x1024 fp32)
// ---------------------------------------------------------------------------
__global__ void prep_kernel(const float* __restrict__ x, unsigned short* __restrict__ xb,
                            const float* __restrict__ Wb, float* __restrict__ Wbt) {
    const int bid = blockIdx.x;
    if (bid < 2048) {
        const int idx = bid * 256 + threadIdx.x;
        const float4 v = ((const float4*)x)[idx];
        ushort4 o;
        o.x = f2bf(v.x); o.y = f2bf(v.y); o.z = f2bf(v.z); o.w = f2bf(v.w);
        ((ushort4*)xb)[idx] = o;
    } else {
        const int t = (bid - 2048) * 256 + threadIdx.x;
        const int h = t >> 10, k = t & 1023;
        Wbt[t] = Wb[k * HH + h];
    }
}

// ---------------------------------------------------------------------------
// transpose+cast the 4 square weights: W[k][n] fp32 -> Wt[n][k] bf16
// ---------------------------------------------------------------------------
__global__ void transpose_cast(const float* __restrict__ W0, const float* __restrict__ W1,
                               const float* __restrict__ W2, const float* __restrict__ W3,
                               unsigned short* __restrict__ T0, unsigned short* __restrict__ T1,
                               unsigned short* __restrict__ T2, unsigned short* __restrict__ T3) {
    __shared__ float tile[32][33];
    const int which = blockIdx.x >> 10;
    const int b = blockIdx.x & 1023;
    const int bk = b >> 5, bn = b & 31;
    const float* W = which == 0 ? W0 : which == 1 ? W1 : which == 2 ? W2 : W3;
    unsigned short* T = which == 0 ? T0 : which == 1 ? T1 : which == 2 ? T2 : T3;
    const int tx = threadIdx.x & 31, ty = threadIdx.x >> 5;
#pragma unroll
    for (int i = 0; i < 4; ++i)
        tile[ty + i * 8][tx] = W[(size_t)(bk * 32 + ty + i * 8) * DD + bn * 32 + tx];
    __syncthreads();
#pragma unroll
    for (int i = 0; i < 4; ++i)
        T[(size_t)(bn * 32 + ty + i * 8) * DD + bk * 32 + tx] = f2bf(tile[tx][ty + i * 8]);
}

// ---------------------------------------------------------------------------
// bf16 MFMA GEMM K-loop (m97 structure): 128x128 tile, BK=32, 256 thr.
// ---------------------------------------------------------------------------
__device__ __forceinline__ void gemm_kloop(const unsigned short* A, const unsigned short* Bt,
                                           unsigned short* As, unsigned short* Bs,
                                           int rowBase, int colBase, int K,
                                           f32x4 acc[4][4]) {
    const int tid = threadIdx.x;
    const int c0 = tid, c1 = tid + 256;
    const int ar0 = c0 >> 2, ak0 = (c0 & 3) << 3;
    const int ar1 = c1 >> 2, ak1 = (c1 & 3) << 3;
    const unsigned short* Ag0 = A + (size_t)(rowBase + ar0) * K + ak0;
    const unsigned short* Ag1 = A + (size_t)(rowBase + ar1) * K + ak1;
    const unsigned short* Bg0 = Bt + (size_t)(colBase + ar0) * K + ak0;
    const unsigned short* Bg1 = Bt + (size_t)(colBase + ar1) * K + ak1;
    unsigned short* Al0 = As + c0 * 8; unsigned short* Al1 = As + c1 * 8;
    unsigned short* Bl0 = Bs + c0 * 8; unsigned short* Bl1 = Bs + c1 * 8;
    const int lane = tid & 63, wv = tid >> 6;
    const int qr = wv >> 1, qc = wv & 1;
    const int fr = lane & 15;
    const int koff = (lane >> 4) << 3;
    int aoff[4], boff[4];
#pragma unroll
    for (int mi = 0; mi < 4; ++mi) aoff[mi] = (qr * 64 + mi * 16 + fr) * 32 + koff;
#pragma unroll
    for (int nj = 0; nj < 4; ++nj) boff[nj] = (qc * 64 + nj * 16 + fr) * 32 + koff;

    for (int k0 = 0; k0 < K; k0 += 32) {
        __syncthreads();
        gload16(Ag0, Al0); gload16(Ag1, Al1);
        gload16(Bg0, Bl0); gload16(Bg1, Bl1);
        Ag0 += 32; Ag1 += 32; Bg0 += 32; Bg1 += 32;
        __syncthreads();
        bf16x8 av[4], bv[4];
#pragma unroll
        for (int mi = 0; mi < 4; ++mi) av[mi] = *(const bf16x8*)(As + aoff[mi]);
#pragma unroll
        for (int nj = 0; nj < 4; ++nj) bv[nj] = *(const bf16x8*)(Bs + boff[nj]);
#pragma unroll
        for (int mi = 0; mi < 4; ++mi)
#pragma unroll
            for (int nj = 0; nj < 4; ++nj)
                acc[mi][nj] = __builtin_amdgcn_mfma_f32_16x16x32_bf16(av[mi], bv[nj], acc[mi][nj], 0, 0, 0);
    }
}

// ---------------------------------------------------------------------------
// Fused q/k/v projection GEMM with per-head L2-norm epilogue for q,k.
// ---------------------------------------------------------------------------
__global__ __launch_bounds__(256) void gemm_qkv(const unsigned short* __restrict__ xb,
                                                const unsigned short* __restrict__ Wqt,
                                                const unsigned short* __restrict__ Wkt,
                                                const unsigned short* __restrict__ Wvt,
                                                unsigned short* __restrict__ qb,
                                                unsigned short* __restrict__ kb,
                                                unsigned short* __restrict__ vb) {
    __shared__ unsigned short As[128 * 32];
    __shared__ unsigned short Bs[128 * 32];
    const int by = blockIdx.x / 24, bxx = blockIdx.x % 24;
    const int mat = bxx >> 3, tn = bxx & 7;
    const unsigned short* Bt = mat == 0 ? Wqt : (mat == 1 ? Wkt : Wvt);
    unsigned short* Cout = mat == 0 ? qb : (mat == 1 ? kb : vb);
    f32x4 acc[4][4];
#pragma unroll
    for (int mi = 0; mi < 4; ++mi)
#pragma unroll
        for (int nj = 0; nj < 4; ++nj) acc[mi][nj] = (f32x4){0.f, 0.f, 0.f, 0.f};
    gemm_kloop(xb, Bt, As, Bs, by * 128, tn * 128, DD, acc);

    const int lane = threadIdx.x & 63, wv = threadIdx.x >> 6;
    const int qr = wv >> 1, qc = wv & 1;
    if (mat < 2) {
#pragma unroll
        for (int mi = 0; mi < 4; ++mi)
#pragma unroll
            for (int i = 0; i < 4; ++i) {
                float s = 0.f;
#pragma unroll
                for (int nj = 0; nj < 4; ++nj) { float t = acc[mi][nj][i]; s += t * t; }
                s += __shfl_xor(s, 1, 64);
                s += __shfl_xor(s, 2, 64);
                s += __shfl_xor(s, 4, 64);
                s += __shfl_xor(s, 8, 64);
                const float inv = 1.0f / fmaxf(sqrtf(s), 1e-12f);
#pragma unroll
                for (int nj = 0; nj < 4; ++nj) acc[mi][nj][i] *= inv;
            }
    }
#pragma unroll
    for (int mi = 0; mi < 4; ++mi)
#pragma unroll
        for (int i = 0; i < 4; ++i) {
            const int row = by * 128 + qr * 64 + mi * 16 + (lane >> 4) * 4 + i;
#pragma unroll
            for (int nj = 0; nj < 4; ++nj) {
                const int col = tn * 128 + qc * 64 + nj * 16 + (lane & 15);
                Cout[(size_t)row * DD + col] = f2bf(acc[mi][nj][i]);
            }
        }
}

// ---------------------------------------------------------------------------
// Output GEMM: out = y(bf16) @ Wo -> fp32. 64x128 tile, grid = 32*8 = 256.
// ---------------------------------------------------------------------------
__global__ __launch_bounds__(256) void gemm_out(const unsigned short* __restrict__ yb,
                                                const unsigned short* __restrict__ Wot,
                                                float* __restrict__ out) {
    __shared__ unsigned short As[64 * 32];
    __shared__ unsigned short Bs[128 * 32];
    const int by = blockIdx.x >> 3, tn = blockIdx.x & 7;
    const int tid = threadIdx.x;
    const int rowBase = by * 64, colBase = tn * 128;
    const int ar = tid >> 2, ak = (tid & 3) << 3;
    const unsigned short* Ag = yb + (size_t)(rowBase + ar) * DD + ak;
    unsigned short* Al = As + tid * 8;
    const int c1 = tid + 256;
    const int br1 = c1 >> 2, bk1 = (c1 & 3) << 3;
    const unsigned short* Bg0 = Wot + (size_t)(colBase + ar) * DD + ak;
    const unsigned short* Bg1 = Wot + (size_t)(colBase + br1) * DD + bk1;
    unsigned short* Bl0 = Bs + tid * 8; unsigned short* Bl1 = Bs + c1 * 8;
    const int lane = tid & 63, wv = tid >> 6;
    const int rh = wv & 1, ch = wv >> 1;
    const int fr = lane & 15, koff = (lane >> 4) << 3;
    int aoff[2], boff[4];
#pragma unroll
    for (int mi = 0; mi < 2; ++mi) aoff[mi] = (rh * 32 + mi * 16 + fr) * 32 + koff;
#pragma unroll
    for (int nj = 0; nj < 4; ++nj) boff[nj] = (ch * 64 + nj * 16 + fr) * 32 + koff;
    f32x4 acc[2][4];
#pragma unroll
    for (int mi = 0; mi < 2; ++mi)
#pragma unroll
        for (int nj = 0; nj < 4; ++nj) acc[mi][nj] = (f32x4){0.f, 0.f, 0.f, 0.f};
    for (int k0 = 0; k0 < DD; k0 += 32) {
        __syncthreads();
        gload16(Ag, Al); gload16(Bg0, Bl0); gload16(Bg1, Bl1);
        Ag += 32; Bg0 += 32; Bg1 += 32;
        __syncthreads();
        bf16x8 av[2], bv[4];
#pragma unroll
        for (int mi = 0; mi < 2; ++mi) av[mi] = *(const bf16x8*)(As + aoff[mi]);
#pragma unroll
        for (int nj = 0; nj < 4; ++nj) bv[nj] = *(const bf16x8*)(Bs + boff[nj]);
#pragma unroll
        for (int mi = 0; mi < 2; ++mi)
#pragma unroll
            for (int nj = 0; nj < 4; ++nj)
                acc[mi][nj] = __builtin_amdgcn_mfma_f32_16x16x32_bf16(av[mi], bv[nj], acc[mi][nj], 0, 0, 0);
    }
    const int quad = lane >> 4;
#pragma unroll
    for (int mi = 0; mi < 2; ++mi)
#pragma unroll
        for (int i = 0; i < 4; ++i) {
            const int row = rowBase + rh * 32 + mi * 16 + quad * 4 + i;
#pragma unroll
            for (int nj = 0; nj < 4; ++nj) {
                const int col = colBase + ch * 64 + nj * 16 + fr;
                out[(size_t)row * DD + col] = acc[mi][nj][i];
            }
        }
}

// ---------------------------------------------------------------------------
// beta[m,h] = sigmoid(x[m,:] @ Wbt[h,:] + bb[h]); one wave per row m.
// ---------------------------------------------------------------------------
__global__ void beta_kernel(const float* __restrict__ x, const float* __restrict__ Wbt,
                            const float* __restrict__ bias, float* __restrict__ beta) {
    const int m = blockIdx.x * 4 + (threadIdx.x >> 6);
    const int lane = threadIdx.x & 63;
    const float4* xr = (const float4*)(x + (size_t)m * DD);
    float4 xv[4];
#pragma unroll
    for (int i = 0; i < 4; ++i) xv[i] = xr[lane * 4 + i];
    float res = 0.f;
#pragma unroll
    for (int h = 0; h < HH; ++h) {
        const float4* wr = (const float4*)(Wbt + (size_t)h * DD);
        float s = 0.f;
#pragma unroll
        for (int i = 0; i < 4; ++i) {
            const float4 w = wr[lane * 4 + i];
            s += xv[i].x * w.x + xv[i].y * w.y + xv[i].z * w.z + xv[i].w * w.w;
        }
        s += __shfl_xor(s, 1, 64);  s += __shfl_xor(s, 2, 64);
        s += __shfl_xor(s, 4, 64);  s += __shfl_xor(s, 8, 64);
        s += __shfl_xor(s, 16, 64); s += __shfl_xor(s, 32, 64);
        if (lane == h) res = s;
    }
    if (lane < HH) beta[m * HH + lane] = 1.0f / (1.0f + expf(-(res + bias[lane])));
}

// ---------------------------------------------------------------------------
// Per-chunk KV sums via MFMA: states[bh][c][d][e] = sum_t (beta*k)[t][d]*v[t][e]
// A = (beta*k)^T [d][t], B = v^T [e][t], both bf16 LDS stride-70.
// ---------------------------------------------------------------------------
__global__ __launch_bounds__(256) void chunkkv_kernel(const unsigned short* __restrict__ k,
                                                      const unsigned short* __restrict__ v,
                                                      const float* __restrict__ beta,
                                                      float* __restrict__ states) {
    const int c = blockIdx.x % NCHK;
    const int bh = blockIdx.x / NCHK;
    const int b = bh / HH, h = bh % HH;
    __shared__ unsigned short kT[64 * 70];
    __shared__ unsigned short vT[64 * 70];
    const int tid = threadIdx.x;
    for (int i = tid; i < 512; i += 256) {
        const int t = i >> 3, dg = (i & 7) << 3;
        const int m = b * LL + c * CHK + t;
        const float be = beta[m * HH + h];
        const size_t go = (size_t)m * DD + h * 64 + dg;
        const uint4 ku = *(const uint4*)&k[go];
        const uint4 vu = *(const uint4*)&v[go];
        unsigned int kw[4] = {ku.x, ku.y, ku.z, ku.w};
        unsigned int vw[4] = {vu.x, vu.y, vu.z, vu.w};
#pragma unroll
        for (int jj = 0; jj < 4; ++jj) {
            kT[(dg + 2 * jj)     * 70 + t] = f2bf(bflo(kw[jj]) * be);
            kT[(dg + 2 * jj + 1) * 70 + t] = f2bf(bfhi(kw[jj]) * be);
            vT[(dg + 2 * jj)     * 70 + t] = (unsigned short)(vw[jj] & 0xffffu);
            vT[(dg + 2 * jj + 1) * 70 + t] = (unsigned short)(vw[jj] >> 16);
        }
    }
    __syncthreads();
    const int lane = tid & 63, wv = tid >> 6;
    const int fr = lane & 15, quad = lane >> 4;
    f32x4 acc[4];
#pragma unroll
    for (int et = 0; et < 4; ++et) acc[et] = (f32x4){0.f, 0.f, 0.f, 0.f};
#pragma unroll
    for (int kh = 0; kh < 2; ++kh) {
        const int tc = kh * 32 + quad * 8;
        const bf16x8 a = frag70(kT, wv * 16 + fr, tc);
#pragma unroll
        for (int et = 0; et < 4; ++et) {
            const bf16x8 bb = frag70(vT, et * 16 + fr, tc);
            acc[et] = __builtin_amdgcn_mfma_f32_16x16x32_bf16(a, bb, acc[et], 0, 0, 0);
        }
    }
    float* outp = states + ((size_t)bh * NCHK + c) * 4096;
#pragma unroll
    for (int et = 0; et < 4; ++et)
#pragma unroll
        for (int i = 0; i < 4; ++i) {
            const int d = wv * 16 + quad * 4 + i;
            const int e = et * 16 + fr;
            outp[d * 64 + e] = acc[et][i];
        }
}

// ---------------------------------------------------------------------------
// Exclusive prefix over chunks. grid = 32 bh * 16 pos-groups = 512 blocks.
// All 16 loads issued before any store (register-buffered).
// ---------------------------------------------------------------------------
__global__ void prefix_kernel(float* __restrict__ states) {
    const int bh = blockIdx.x >> 4, pg = blockIdx.x & 15;
    float* base = states + (size_t)bh * NCHK * 4096 + pg * 256 + threadIdx.x;
    float vals[NCHK];
#pragma unroll
    for (int c = 0; c < NCHK; ++c) vals[c] = base[c * 4096];
    float run = 0.0f;
#pragma unroll
    for (int c = 0; c < NCHK; ++c) {
        base[c * 4096] = run;
        run += vals[c];
    }
}

// ---------------------------------------------------------------------------
// Per-chunk output via MFMA:
// S = q@k^T (masked) -> P bf16; O = P@(beta*v) + q@st -> y bf16.
// ---------------------------------------------------------------------------
__global__ __launch_bounds__(256) void attn_kernel(const unsigned short* __restrict__ q,
                                                   const unsigned short* __restrict__ k,
                                                   const unsigned short* __restrict__ v,
                                                   const float* __restrict__ beta,
                                                   const float* __restrict__ states,
                                                   unsigned short* __restrict__ y) {
    const int c = blockIdx.x % NCHK;
    const int bh = blockIdx.x / NCHK;
    const int b = bh / HH, h = bh % HH;
    __shared__ unsigned short qS[64 * 80];   // [t][d], stride 80 (16B-aligned rows)
    __shared__ unsigned short kS[64 * 80];   // [s][d]
    __shared__ unsigned short sS[64 * 80];   // masked P [t][s]
    __shared__ unsigned short vT[64 * 70];   // (beta*v)^T [e][s]
    __shared__ unsigned short sT[64 * 70];   // st^T [e][d]
    const int tid = threadIdx.x;
    const float* stg = states + ((size_t)bh * NCHK + c) * 4096;
    for (int i = tid; i < 512; i += 256) {
        const int t = i >> 3, dg = (i & 7) << 3;
        const int m = b * LL + c * CHK + t;
        const float be = beta[m * HH + h];
        const size_t go = (size_t)m * DD + h * 64 + dg;
        const uint4 qu = *(const uint4*)&q[go];
        const uint4 ku = *(const uint4*)&k[go];
        const uint4 vu = *(const uint4*)&v[go];
        *(uint4*)&qS[t * 80 + dg] = qu;
        *(uint4*)&kS[t * 80 + dg] = ku;
        unsigned int vw[4] = {vu.x, vu.y, vu.z, vu.w};
#pragma unroll
        for (int jj = 0; jj < 4; ++jj) {
            vT[(dg + 2 * jj)     * 70 + t] = f2bf(bflo(vw[jj]) * be);
            vT[(dg + 2 * jj + 1) * 70 + t] = f2bf(bfhi(vw[jj]) * be);
        }
    }
    for (int i = tid; i < 1024; i += 256) {
        const int d = i >> 4, eg = (i & 15) << 2;
        const float4 s4 = ((const float4*)stg)[i];
        sT[(eg + 0) * 70 + d] = f2bf(s4.x);
        sT[(eg + 1) * 70 + d] = f2bf(s4.y);
        sT[(eg + 2) * 70 + d] = f2bf(s4.z);
        sT[(eg + 3) * 70 + d] = f2bf(s4.w);
    }
    __syncthreads();
    const int lane = tid & 63, wv = tid >> 6;
    const int fr = lane & 15, quad = lane >> 4;
    const int koff = quad * 8;
    // phase 1: S row-tile wv (rows wv*16..+15), all 4 col-tiles
    f32x4 s_acc[4];
#pragma unroll
    for (int j = 0; j < 4; ++j) s_acc[j] = (f32x4){0.f, 0.f, 0.f, 0.f};
#pragma unroll
    for (int kh = 0; kh < 2; ++kh) {
        const bf16x8 a = *(const bf16x8*)&qS[(wv * 16 + fr) * 80 + kh * 32 + koff];
#pragma unroll
        for (int j = 0; j < 4; ++j) {
            const bf16x8 bb = *(const bf16x8*)&kS[(j * 16 + fr) * 80 + kh * 32 + koff];
            s_acc[j] = __builtin_amdgcn_mfma_f32_16x16x32_bf16(a, bb, s_acc[j], 0, 0, 0);
        }
    }
    // mask + store P (bf16). Rows written == rows this wave reads below: no barrier.
#pragma unroll
    for (int j = 0; j < 4; ++j)
#pragma unroll
        for (int i = 0; i < 4; ++i) {
            const int t = wv * 16 + quad * 4 + i;
            const int s = j * 16 + fr;
            sS[t * 80 + s] = (s <= t) ? f2bf(s_acc[j][i]) : (unsigned short)0;
        }
    // phase 2: O = P@vT + q@sT
    f32x4 o_acc[4];
#pragma unroll
    for (int j = 0; j < 4; ++j) o_acc[j] = (f32x4){0.f, 0.f, 0.f, 0.f};
#pragma unroll
    for (int kh = 0; kh < 2; ++kh) {
        const bf16x8 a = *(const bf16x8*)&sS[(wv * 16 + fr) * 80 + kh * 32 + koff];
#pragma unroll
        for (int j = 0; j < 4; ++j) {
            const bf16x8 bb = frag70(vT, j * 16 + fr, kh * 32 + koff);
            o_acc[j] = __builtin_amdgcn_mfma_f32_16x16x32_bf16(a, bb, o_acc[j], 0, 0, 0);
        }
    }
#pragma unroll
    for (int kh = 0; kh < 2; ++kh) {
        const bf16x8 a = *(const bf16x8*)&qS[(wv * 16 + fr) * 80 + kh * 32 + koff];
#pragma unroll
        for (int j = 0; j < 4; ++j) {
            const bf16x8 bb = frag70(sT, j * 16 + fr, kh * 32 + koff);
            o_acc[j] = __builtin_amdgcn_mfma_f32_16x16x32_bf16(a, bb, o_acc[j], 0, 0, 0);
        }
    }
#pragma unroll
    for (int j = 0; j < 4; ++j)
#pragma unroll
        for (int i = 0; i < 4; ++i) {
            const int m = b * LL + c * CHK + wv * 16 + quad * 4 + i;
            const int e = j * 16 + fr;
            y[(size_t)m * DD + h * 64 + e] = f2bf(o_acc[j][i]);
        }
}

// ---------------------------------------------------------------------------
extern "C" void kernel_launch(void* const* d_in, const int* in_sizes, int n_in,
                              void* d_out, int out_size, void* d_ws, size_t ws_size,
                              hipStream_t stream) {
    (void)in_sizes; (void)n_in; (void)out_size; (void)ws_size;
    const float* x  = (const float*)d_in[0];
    const float* Wq = (const float*)d_in[1];
    const float* Wk = (const float*)d_in[2];
    const float* Wv = (const float*)d_in[3];
    const float* Wo = (const float*)d_in[4];
    const float* Wb = (const float*)d_in[5];
    const float* bbp = (const float*)d_in[6];
    float* out = (float*)d_out;

    char* ws = (char*)d_ws;
    unsigned short* xb  = (unsigned short*)ws;                      ws += (size_t)MM * DD * 2;
    unsigned short* Wqt = (unsigned short*)ws;                      ws += (size_t)DD * DD * 2;
    unsigned short* Wkt = (unsigned short*)ws;                      ws += (size_t)DD * DD * 2;
    unsigned short* Wvt = (unsigned short*)ws;                      ws += (size_t)DD * DD * 2;
    unsigned short* Wot = (unsigned short*)ws;                      ws += (size_t)DD * DD * 2;
    float*          Wbt = (float*)ws;                               ws += (size_t)HH * DD * 4;
    unsigned short* qb  = (unsigned short*)ws;                      ws += (size_t)MM * DD * 2;
    unsigned short* kb  = (unsigned short*)ws;                      ws += (size_t)MM * DD * 2;
    unsigned short* vb  = (unsigned short*)ws;                      ws += (size_t)MM * DD * 2;
    unsigned short* yb  = (unsigned short*)ws;                      ws += (size_t)MM * DD * 2;
    float*          beta   = (float*)ws;                            ws += (size_t)MM * HH * 4;
    float*          states = (float*)ws;                            ws += (size_t)BB * HH * NCHK * 4096 * 4;

    prep_kernel<<<2112, 256, 0, stream>>>(x, xb, Wb, Wbt);
    transpose_cast<<<4096, 256, 0, stream>>>(Wq, Wk, Wv, Wo, Wqt, Wkt, Wvt, Wot);
    gemm_qkv<<<16 * 24, 256, 0, stream>>>(xb, Wqt, Wkt, Wvt, qb, kb, vb);
    beta_kernel<<<MM / 4, 256, 0, stream>>>(x, Wbt, bbp, beta);
    chunkkv_kernel<<<BB * HH * NCHK, 256, 0, stream>>>(kb, vb, beta, states);
    prefix_kernel<<<BB * HH * NCHK, 256, 0, stream>>>(states);
    attn_kernel<<<BB * HH * NCHK, 256, 0, stream>>>(qb, kb, vb, beta, states, yb);
    gemm_out<<<32 * 8, 256, 0, stream>>>(yb, Wot, out);
}